// Round 20
// baseline (226.277 us; speedup 1.0000x reference)
//
#include <hip/hip_runtime.h>

#define N_NODES 100000
#define N_EDGES 3200000
#define N_GRAPHS 2048
#define SSH 8                       // 256 dst nodes per superbucket
#define SSZ 256
#define NSB 391                     // ceil(100000/256)
#define CAP 12800                   // slots per superbucket region (mult of 16)
#define WC_BLOCKS 256
#define WC_THREADS 1024
#define WC_EPB 12500                // N_EDGES / WC_BLOCKS
#define WC_SUB 4096
#define CAPB 56                     // per-bin LDS write-combine buffer entries
#define SENT 0xFFFFFFFFu
#define NPB 391                     // nodes per agg block (grid=256, balanced)

__device__ __forceinline__ void gAtomAdd(float* p, float v) { unsafeAtomicAdd(p, v); }

// ---------- fused fill with software write-combining (proven r19) ----------
__global__ void kAB_wc(const int* __restrict__ src, const int* __restrict__ dst,
                       int* __restrict__ bpad, int* __restrict__ rcnt,
                       unsigned* __restrict__ stage) {
  __shared__ int lbase[NSB], ctr[NSB];
  extern __shared__ unsigned buf[];              // [NSB][CAPB], 87.6 KB dynamic
  int tid = threadIdx.x, blk = blockIdx.x;
  int beg = blk * WC_EPB, end = beg + WC_EPB;
  for (int i = tid; i < NSB; i += WC_THREADS) ctr[i] = 0;
  __syncthreads();
  for (int e = beg + tid; e < end; e += WC_THREADS)
    atomicAdd(&ctr[dst[e] >> SSH], 1);
  __syncthreads();
  for (int i = tid; i < NSB; i += WC_THREADS) {
    int h = ctr[i];
    int hp = (h + 15) & ~15;
    int base = 0;
    if (hp) base = atomicAdd(&bpad[i], hp);
    if (h) atomicAdd(&rcnt[i], h);
    lbase[i] = i * CAP + base;
    ctr[i] = 0;
  }
  __syncthreads();
  for (int sc = 0; sc < WC_EPB; sc += WC_SUB) {
    int send = beg + sc + WC_SUB; if (send > end) send = end;
    for (int e = beg + sc + tid; e < send; e += WC_THREADS) {
      int d = dst[e], s = src[e];
      int b = d >> SSH;
      int pos = atomicAdd(&ctr[b], 1);
      buf[b * CAPB + pos] = ((unsigned)s << SSH) | (unsigned)(d & (SSZ - 1));
    }
    __syncthreads();
    for (int b = tid; b < NSB; b += WC_THREADS) {
      int c = ctr[b];
      int g = c >> 4;
      if (g) {
        unsigned* bb = &buf[b * CAPB];
        int gb = lbase[b];
        for (int q = 0; q < g; q++) {
          uint4* dp = (uint4*)&stage[gb + q * 16];
          const uint4* sp = (const uint4*)&bb[q * 16];
          dp[0] = sp[0]; dp[1] = sp[1]; dp[2] = sp[2]; dp[3] = sp[3];
        }
        lbase[b] = gb + g * 16;
        int rem = c & 15;
        for (int j = 0; j < rem; j++) bb[j] = bb[g * 16 + j];
        ctr[b] = rem;
      }
    }
    __syncthreads();
  }
  for (int b = tid; b < NSB; b += WC_THREADS) {
    int c = ctr[b];
    if (c) {
      unsigned* bb = &buf[b * CAPB];
      for (int j = c; j < 16; j++) bb[j] = SENT;
      uint4* dp = (uint4*)&stage[lbase[b]];
      const uint4* sp = (const uint4*)bb;
      dp[0] = sp[0]; dp[1] = sp[1]; dp[2] = sp[2]; dp[3] = sp[3];
    }
  }
}

// ---------- exclusive scan over NSB REAL counts (proven) ----------
__global__ void k_bscan(const int* __restrict__ rcnt, int* __restrict__ sboffs) {
  __shared__ int sh[512];
  int tid = threadIdx.x;
  int v = (tid < NSB) ? rcnt[tid] : 0;
  sh[tid] = v;
  __syncthreads();
  for (int off = 1; off < 512; off <<= 1) {
    int t = (tid >= off) ? sh[tid - off] : 0;
    __syncthreads();
    sh[tid] += t;
    __syncthreads();
  }
  if (tid < NSB) sboffs[tid] = sh[tid] - v;
  if (tid == 0) sboffs[NSB] = N_EDGES;
}

// ---------- per-superbucket node sort -> dense csr + noffs + dinv + xd8 (proven) ----------
__global__ void kC_csr(const unsigned* __restrict__ stage, const int* __restrict__ bpad,
                       const int* __restrict__ sboffs, const float* __restrict__ x,
                       int* __restrict__ noffs, float* __restrict__ dinv,
                       float* __restrict__ xd8, int* __restrict__ csr) {
  __shared__ int cnt[SSZ], sc[SSZ], cur[SSZ];
  int b = blockIdx.x, tid = threadIdx.x;
  cnt[tid] = 0;
  __syncthreads();
  size_t rbeg = (size_t)b * CAP;
  int pcnt = bpad[b];
  int wbeg = sboffs[b];
  for (int k = tid; k < pcnt; k += 256) {
    unsigned u = stage[rbeg + k];
    if (u != SENT) atomicAdd(&cnt[u & (SSZ - 1)], 1);
  }
  __syncthreads();
  sc[tid] = cnt[tid];
  __syncthreads();
  for (int off = 1; off < SSZ; off <<= 1) {
    int t = (tid >= off) ? sc[tid - off] : 0;
    __syncthreads();
    sc[tid] += t;
    __syncthreads();
  }
  int excl = sc[tid] - cnt[tid];
  int node = b * SSZ + tid;
  if (node <= N_NODES) noffs[node] = wbeg + excl;
  if (node < N_NODES) {
    float di = rsqrtf((float)(cnt[tid] + 1));    // +1 self-loop
    dinv[node] = di;
    float r[5];
#pragma unroll
    for (int c = 0; c < 5; c++) r[c] = x[node * 5 + c] * di;
    float4* xv = (float4*)xd8;
    xv[node * 2]     = make_float4(r[0], r[1], r[2], r[3]);
    xv[node * 2 + 1] = make_float4(r[4], 0.f, 0.f, 0.f);
  }
  cur[tid] = wbeg + excl;
  __syncthreads();
  for (int k = tid; k < pcnt; k += 256) {
    unsigned u = stage[rbeg + k];
    if (u != SENT) {
      int pos = atomicAdd(&cur[u & (SSZ - 1)], 1);
      csr[pos] = (int)(u >> SSH);
    }
  }
}

// ---------- layer-1: balanced 256-block grid, contiguous 391-node range per block ----------
__global__ void k_agg1(const int* __restrict__ csr, const int* __restrict__ noffs,
                       const float* __restrict__ xd8, const float* __restrict__ dinv,
                       const float* __restrict__ W1, const float* __restrict__ b1,
                       const float* __restrict__ W2, float* __restrict__ g2) {
  __shared__ float w1[150], bb1[30], w2[240];
  int tid = threadIdx.x;
  for (int i = tid; i < 150; i += 256) w1[i] = W1[i];
  for (int i = tid; i < 30; i += 256) bb1[i] = b1[i];
  for (int i = tid; i < 240; i += 256) w2[i] = W2[i];
  __syncthreads();
  int n0 = blockIdx.x * NPB;
  int nend = n0 + NPB; if (nend > N_NODES) nend = N_NODES;
  const float4* xv = (const float4*)xd8;
  for (int n = n0 + tid; n < nend; n += 256) {
    float a0 = 0, a1 = 0, a2 = 0, a3 = 0, a4 = 0;
    int k = noffs[n], end = noffs[n + 1];
    for (; k + 4 <= end; k += 4) {
      int s0 = csr[k], s1 = csr[k + 1], s2 = csr[k + 2], s3 = csr[k + 3];
      float4 q0 = xv[s0 * 2], q1 = xv[s1 * 2], q2 = xv[s2 * 2], q3 = xv[s3 * 2];
      float c0 = xd8[s0 * 8 + 4], c1 = xd8[s1 * 8 + 4], c2 = xd8[s2 * 8 + 4], c3 = xd8[s3 * 8 + 4];
      a0 += q0.x + q1.x + q2.x + q3.x;
      a1 += q0.y + q1.y + q2.y + q3.y;
      a2 += q0.z + q1.z + q2.z + q3.z;
      a3 += q0.w + q1.w + q2.w + q3.w;
      a4 += c0 + c1 + c2 + c3;
    }
    for (; k < end; k++) {
      int s = csr[k];
      float4 q = xv[s * 2];
      a0 += q.x; a1 += q.y; a2 += q.z; a3 += q.w; a4 += xd8[s * 8 + 4];
    }
    float di = dinv[n];
    float t[5] = {(a0 + xd8[n * 8 + 0]) * di, (a1 + xd8[n * 8 + 1]) * di,
                  (a2 + xd8[n * 8 + 2]) * di, (a3 + xd8[n * 8 + 3]) * di,
                  (a4 + xd8[n * 8 + 4]) * di};
    float h[30];
#pragma unroll
    for (int j = 0; j < 30; j++) h[j] = bb1[j];
#pragma unroll
    for (int kk = 0; kk < 5; kk++)
#pragma unroll
      for (int j = 0; j < 30; j++) h[j] += t[kk] * w1[kk * 30 + j];
    float g[8] = {0, 0, 0, 0, 0, 0, 0, 0};
#pragma unroll
    for (int j = 0; j < 30; j++) {
      float hj = fmaxf(h[j], 0.f);
#pragma unroll
      for (int c = 0; c < 8; c++) g[c] += hj * w2[j * 8 + c];
    }
    float4* gv = (float4*)g2;
    gv[n * 2]     = make_float4(g[0] * di, g[1] * di, g[2] * di, g[3] * di);
    gv[n * 2 + 1] = make_float4(g[4] * di, g[5] * di, g[6] * di, g[7] * di);
  }
}

// ---------- layer-2: balanced 256-block grid + fused pooling ----------
__global__ void k_agg2(const int* __restrict__ csr, const int* __restrict__ noffs,
                       const float* __restrict__ g2, const float* __restrict__ dinv,
                       const float* __restrict__ b2, const int* __restrict__ batch,
                       float* __restrict__ gsum) {
  __shared__ float gpool[64 * 8];
  __shared__ float bb2[8];
  __shared__ int batch0s;
  int blk = blockIdx.x, tid = threadIdx.x;
  for (int i = tid; i < 64 * 8; i += 256) gpool[i] = 0.f;
  if (tid < 8) bb2[tid] = b2[tid];
  int n0 = blk * NPB;
  int nend = n0 + NPB; if (nend > N_NODES) nend = N_NODES;
  if (tid == 0) batch0s = batch[n0 < N_NODES ? n0 : (N_NODES - 1)];
  __syncthreads();
  int batch0 = batch0s;
  const float4* gv = (const float4*)g2;
  for (int n = n0 + tid; n < nend; n += 256) {
    float4 lo = make_float4(0, 0, 0, 0), hi = make_float4(0, 0, 0, 0);
    int k = noffs[n], end = noffs[n + 1];
    for (; k + 2 <= end; k += 2) {
      int s0 = csr[k], s1 = csr[k + 1];
      float4 p0 = gv[s0 * 2], q0 = gv[s0 * 2 + 1];
      float4 p1 = gv[s1 * 2], q1 = gv[s1 * 2 + 1];
      lo.x += p0.x + p1.x; lo.y += p0.y + p1.y;
      lo.z += p0.z + p1.z; lo.w += p0.w + p1.w;
      hi.x += q0.x + q1.x; hi.y += q0.y + q1.y;
      hi.z += q0.z + q1.z; hi.w += q0.w + q1.w;
    }
    for (; k < end; k++) {
      int s = csr[k];
      float4 p = gv[s * 2], q = gv[s * 2 + 1];
      lo.x += p.x; lo.y += p.y; lo.z += p.z; lo.w += p.w;
      hi.x += q.x; hi.y += q.y; hi.z += q.z; hi.w += q.w;
    }
    float di = dinv[n];
    float4 sl = gv[n * 2], sh = gv[n * 2 + 1];   // self-loop
    float val[8] = {di * (lo.x + sl.x) + bb2[0], di * (lo.y + sl.y) + bb2[1],
                    di * (lo.z + sl.z) + bb2[2], di * (lo.w + sl.w) + bb2[3],
                    di * (hi.x + sh.x) + bb2[4], di * (hi.y + sh.y) + bb2[5],
                    di * (hi.z + sh.z) + bb2[6], di * (hi.w + sh.w) + bb2[7]};
    int gid = batch[n], goff = gid - batch0;
#pragma unroll
    for (int c = 0; c < 8; c++) {
      if (goff >= 0 && goff < 64) atomicAdd(&gpool[goff * 8 + c], val[c]);
      else                        gAtomAdd(&gsum[gid * 8 + c], val[c]);
    }
  }
  __syncthreads();
  for (int i = tid; i < 64 * 8; i += 256) {
    int gid = batch0 + (i >> 3);
    float v = gpool[i];
    if (gid < N_GRAPHS && v != 0.f) gAtomAdd(&gsum[gid * 8 + (i & 7)], v);
  }
}

// ---------- mean divide (proven) ----------
__global__ void k_final(const float* __restrict__ gsum, const int* __restrict__ batch,
                        float* __restrict__ out) {
  int i = blockIdx.x * 256 + threadIdx.x;
  if (i >= N_GRAPHS * 8) return;
  int g = i >> 3;
  int lo = 0, hi = N_NODES;
  while (lo < hi) { int m = (lo + hi) >> 1; if (batch[m] < g) lo = m + 1; else hi = m; }
  int lo2 = lo, hi2 = N_NODES;
  while (lo2 < hi2) { int m = (lo2 + hi2) >> 1; if (batch[m] <= g) lo2 = m + 1; else hi2 = m; }
  float c = (float)(lo2 - lo);
  out[i] = gsum[i] / fmaxf(c, 1.f);
}

extern "C" void kernel_launch(void* const* d_in, const int* in_sizes, int n_in,
                              void* d_out, int out_size, void* d_ws, size_t ws_size,
                              hipStream_t stream) {
  const float* x    = (const float*)d_in[0];
  const int* ei     = (const int*)d_in[1];
  const int* batch  = (const int*)d_in[2];
  const float* W1   = (const float*)d_in[3];
  const float* b1   = (const float*)d_in[4];
  const float* W2   = (const float*)d_in[5];
  const float* b2   = (const float*)d_in[6];
  const int* srcp = ei;
  const int* dstp = ei + N_EDGES;
  float* out = (float*)d_out;

  // workspace carve (~41 MB)
  char* base = (char*)d_ws;
  size_t o = 0;
  auto carve = [&](size_t bytes) -> char* {
    char* p = base + o;
    o += (bytes + 255) & ~(size_t)255;
    return p;
  };
  int* bpad        = (int*)carve((size_t)NSB * 4);
  int* rcnt        = (int*)carve((size_t)NSB * 4);
  int* sboffs      = (int*)carve((size_t)(NSB + 1) * 4);
  unsigned* stage  = (unsigned*)carve((size_t)NSB * CAP * 4);
  int* csr         = (int*)carve((size_t)N_EDGES * 4);
  int* noffs       = (int*)carve((size_t)(N_NODES + 2) * 4);
  float* dinv      = (float*)carve((size_t)N_NODES * 4);
  float* xd8       = (float*)carve((size_t)N_NODES * 8 * 4);
  float* g2        = (float*)carve((size_t)N_NODES * 8 * 4);
  float* gsum      = (float*)carve((size_t)N_GRAPHS * 8 * 4);

  (void)hipFuncSetAttribute(reinterpret_cast<const void*>(&kAB_wc),
                            hipFuncAttributeMaxDynamicSharedMemorySize,
                            NSB * CAPB * 4);

  hipMemsetAsync(bpad, 0, (size_t)NSB * 4, stream);
  hipMemsetAsync(rcnt, 0, (size_t)NSB * 4, stream);
  hipMemsetAsync(gsum, 0, (size_t)N_GRAPHS * 8 * 4, stream);

  kAB_wc<<<WC_BLOCKS, WC_THREADS, NSB * CAPB * 4, stream>>>(srcp, dstp, bpad, rcnt, stage);
  k_bscan<<<1, 512, 0, stream>>>(rcnt, sboffs);
  kC_csr<<<NSB, 256, 0, stream>>>(stage, bpad, sboffs, x, noffs, dinv, xd8, csr);
  k_agg1<<<256, 256, 0, stream>>>(csr, noffs, xd8, dinv, W1, b1, W2, g2);
  k_agg2<<<256, 256, 0, stream>>>(csr, noffs, g2, dinv, b2, batch, gsum);
  k_final<<<64, 256, 0, stream>>>(gsum, batch, out);
}

// Round 21
// 184.916 us; speedup vs baseline: 1.2237x; 1.2237x over previous
//
#include <hip/hip_runtime.h>

#define N_NODES 100000
#define N_EDGES 3200000
#define N_GRAPHS 2048
#define SSH 8                       // 256 dst nodes per superbucket
#define SSZ 256
#define NSB 391                     // ceil(100000/256)
#define CAP 12800                   // slots per superbucket region (mult of 16)
#define WC_BLOCKS 256
#define WC_THREADS 1024
#define WC_EPB 12500                // N_EDGES / WC_BLOCKS
#define WC_SUB 4096
#define CAPB 56                     // per-bin LDS write-combine buffer entries
#define SENT 0xFFFFFFFFu

__device__ __forceinline__ void gAtomAdd(float* p, float v) { unsafeAtomicAdd(p, v); }

// ---------- fused fill with software write-combining (proven r19) ----------
__global__ void kAB_wc(const int* __restrict__ src, const int* __restrict__ dst,
                       int* __restrict__ bpad, int* __restrict__ rcnt,
                       unsigned* __restrict__ stage) {
  __shared__ int lbase[NSB], ctr[NSB];
  extern __shared__ unsigned buf[];              // [NSB][CAPB], 87.6 KB dynamic
  int tid = threadIdx.x, blk = blockIdx.x;
  int beg = blk * WC_EPB, end = beg + WC_EPB;
  for (int i = tid; i < NSB; i += WC_THREADS) ctr[i] = 0;
  __syncthreads();
  for (int e = beg + tid; e < end; e += WC_THREADS)       // phase 1: histogram
    atomicAdd(&ctr[dst[e] >> SSH], 1);
  __syncthreads();
  for (int i = tid; i < NSB; i += WC_THREADS) {           // padded reservation
    int h = ctr[i];
    int hp = (h + 15) & ~15;
    int base = 0;
    if (hp) base = atomicAdd(&bpad[i], hp);
    if (h) atomicAdd(&rcnt[i], h);
    lbase[i] = i * CAP + base;                  // 16-aligned (CAP%16==0, hp%16==0)
    ctr[i] = 0;
  }
  __syncthreads();
  for (int sc = 0; sc < WC_EPB; sc += WC_SUB) {
    int send = beg + sc + WC_SUB; if (send > end) send = end;
    for (int e = beg + sc + tid; e < send; e += WC_THREADS) {   // append
      int d = dst[e], s = src[e];
      int b = d >> SSH;
      int pos = atomicAdd(&ctr[b], 1);
      buf[b * CAPB + pos] = ((unsigned)s << SSH) | (unsigned)(d & (SSZ - 1));
    }
    __syncthreads();
    for (int b = tid; b < NSB; b += WC_THREADS) {               // flush full groups
      int c = ctr[b];
      int g = c >> 4;
      if (g) {
        unsigned* bb = &buf[b * CAPB];
        int gb = lbase[b];
        for (int q = 0; q < g; q++) {
          uint4* dp = (uint4*)&stage[gb + q * 16];
          const uint4* sp = (const uint4*)&bb[q * 16];
          dp[0] = sp[0]; dp[1] = sp[1]; dp[2] = sp[2]; dp[3] = sp[3];  // one 64B line
        }
        lbase[b] = gb + g * 16;
        int rem = c & 15;
        for (int j = 0; j < rem; j++) bb[j] = bb[g * 16 + j];
        ctr[b] = rem;
      }
    }
    __syncthreads();
  }
  for (int b = tid; b < NSB; b += WC_THREADS) {                 // final sentinel-padded flush
    int c = ctr[b];
    if (c) {
      unsigned* bb = &buf[b * CAPB];
      for (int j = c; j < 16; j++) bb[j] = SENT;
      uint4* dp = (uint4*)&stage[lbase[b]];
      const uint4* sp = (const uint4*)bb;
      dp[0] = sp[0]; dp[1] = sp[1]; dp[2] = sp[2]; dp[3] = sp[3];
    }
  }
}

// ---------- exclusive scan over NSB REAL counts (proven) ----------
__global__ void k_bscan(const int* __restrict__ rcnt, int* __restrict__ sboffs) {
  __shared__ int sh[512];
  int tid = threadIdx.x;
  int v = (tid < NSB) ? rcnt[tid] : 0;
  sh[tid] = v;
  __syncthreads();
  for (int off = 1; off < 512; off <<= 1) {
    int t = (tid >= off) ? sh[tid - off] : 0;
    __syncthreads();
    sh[tid] += t;
    __syncthreads();
  }
  if (tid < NSB) sboffs[tid] = sh[tid] - v;
  if (tid == 0) sboffs[NSB] = N_EDGES;
}

// ---------- per-superbucket node sort -> dense csr + noffs + dinv + xd8 (proven) ----------
__global__ void kC_csr(const unsigned* __restrict__ stage, const int* __restrict__ bpad,
                       const int* __restrict__ sboffs, const float* __restrict__ x,
                       int* __restrict__ noffs, float* __restrict__ dinv,
                       float* __restrict__ xd8, int* __restrict__ csr) {
  __shared__ int cnt[SSZ], sc[SSZ], cur[SSZ];
  int b = blockIdx.x, tid = threadIdx.x;
  cnt[tid] = 0;
  __syncthreads();
  size_t rbeg = (size_t)b * CAP;
  int pcnt = bpad[b];                            // padded slot count
  int wbeg = sboffs[b];
  for (int k = tid; k < pcnt; k += 256) {
    unsigned u = stage[rbeg + k];
    if (u != SENT) atomicAdd(&cnt[u & (SSZ - 1)], 1);
  }
  __syncthreads();
  sc[tid] = cnt[tid];
  __syncthreads();
  for (int off = 1; off < SSZ; off <<= 1) {      // inclusive scan over 256
    int t = (tid >= off) ? sc[tid - off] : 0;
    __syncthreads();
    sc[tid] += t;
    __syncthreads();
  }
  int excl = sc[tid] - cnt[tid];
  int node = b * SSZ + tid;
  if (node <= N_NODES) noffs[node] = wbeg + excl;
  if (node < N_NODES) {
    float di = rsqrtf((float)(cnt[tid] + 1));    // +1 self-loop
    dinv[node] = di;
    float r[5];
#pragma unroll
    for (int c = 0; c < 5; c++) r[c] = x[node * 5 + c] * di;
    float4* xv = (float4*)xd8;
    xv[node * 2]     = make_float4(r[0], r[1], r[2], r[3]);
    xv[node * 2 + 1] = make_float4(r[4], 0.f, 0.f, 0.f);
  }
  cur[tid] = wbeg + excl;
  __syncthreads();
  for (int k = tid; k < pcnt; k += 256) {
    unsigned u = stage[rbeg + k];
    if (u != SENT) {
      int pos = atomicAdd(&cur[u & (SSZ - 1)], 1);
      csr[pos] = (int)(u >> SSH);
    }
  }
}

// ---------- layer-1: per-node register accumulation + fused MLP (proven) ----------
__global__ void k_agg1(const int* __restrict__ csr, const int* __restrict__ noffs,
                       const float* __restrict__ xd8, const float* __restrict__ dinv,
                       const float* __restrict__ W1, const float* __restrict__ b1,
                       const float* __restrict__ W2, float* __restrict__ g2) {
  __shared__ float w1[150], bb1[30], w2[240];
  int tid = threadIdx.x;
  for (int i = tid; i < 150; i += 256) w1[i] = W1[i];
  for (int i = tid; i < 30; i += 256) bb1[i] = b1[i];
  for (int i = tid; i < 240; i += 256) w2[i] = W2[i];
  __syncthreads();
  int n = blockIdx.x * 256 + tid;
  if (n >= N_NODES) return;
  const float4* xv = (const float4*)xd8;
  float a0 = 0, a1 = 0, a2 = 0, a3 = 0, a4 = 0;
  int k = noffs[n], end = noffs[n + 1];
  for (; k + 4 <= end; k += 4) {
    int s0 = csr[k], s1 = csr[k + 1], s2 = csr[k + 2], s3 = csr[k + 3];
    float4 q0 = xv[s0 * 2], q1 = xv[s1 * 2], q2 = xv[s2 * 2], q3 = xv[s3 * 2];
    float c0 = xd8[s0 * 8 + 4], c1 = xd8[s1 * 8 + 4], c2 = xd8[s2 * 8 + 4], c3 = xd8[s3 * 8 + 4];
    a0 += q0.x + q1.x + q2.x + q3.x;
    a1 += q0.y + q1.y + q2.y + q3.y;
    a2 += q0.z + q1.z + q2.z + q3.z;
    a3 += q0.w + q1.w + q2.w + q3.w;
    a4 += c0 + c1 + c2 + c3;
  }
  for (; k < end; k++) {
    int s = csr[k];
    float4 q = xv[s * 2];
    a0 += q.x; a1 += q.y; a2 += q.z; a3 += q.w; a4 += xd8[s * 8 + 4];
  }
  float di = dinv[n];
  float t[5] = {(a0 + xd8[n * 8 + 0]) * di, (a1 + xd8[n * 8 + 1]) * di,
                (a2 + xd8[n * 8 + 2]) * di, (a3 + xd8[n * 8 + 3]) * di,
                (a4 + xd8[n * 8 + 4]) * di};
  float h[30];
#pragma unroll
  for (int j = 0; j < 30; j++) h[j] = bb1[j];
#pragma unroll
  for (int kk = 0; kk < 5; kk++)
#pragma unroll
    for (int j = 0; j < 30; j++) h[j] += t[kk] * w1[kk * 30 + j];
  float g[8] = {0, 0, 0, 0, 0, 0, 0, 0};
#pragma unroll
  for (int j = 0; j < 30; j++) {
    float hj = fmaxf(h[j], 0.f);
#pragma unroll
    for (int c = 0; c < 8; c++) g[c] += hj * w2[j * 8 + c];
  }
  float4* gv = (float4*)g2;
  gv[n * 2]     = make_float4(g[0] * di, g[1] * di, g[2] * di, g[3] * di);
  gv[n * 2 + 1] = make_float4(g[4] * di, g[5] * di, g[6] * di, g[7] * di);
}

// ---------- layer-2: per-node register accumulation + fused pooling (proven) ----------
__global__ void k_agg2(const int* __restrict__ csr, const int* __restrict__ noffs,
                       const float* __restrict__ g2, const float* __restrict__ dinv,
                       const float* __restrict__ b2, const int* __restrict__ batch,
                       float* __restrict__ gsum) {
  __shared__ float gpool[64 * 8];
  __shared__ float bb2[8];
  __shared__ int batch0s;
  int blk = blockIdx.x, tid = threadIdx.x;
  for (int i = tid; i < 64 * 8; i += 256) gpool[i] = 0.f;
  if (tid < 8) bb2[tid] = b2[tid];
  if (tid == 0) {
    int n0 = blk * 256;
    batch0s = batch[n0 < N_NODES ? n0 : (N_NODES - 1)];
  }
  __syncthreads();
  int n = blk * 256 + tid;
  int batch0 = batch0s;
  if (n < N_NODES) {
    const float4* gv = (const float4*)g2;
    float4 lo = make_float4(0, 0, 0, 0), hi = make_float4(0, 0, 0, 0);
    int k = noffs[n], end = noffs[n + 1];
    for (; k + 2 <= end; k += 2) {
      int s0 = csr[k], s1 = csr[k + 1];
      float4 p0 = gv[s0 * 2], q0 = gv[s0 * 2 + 1];
      float4 p1 = gv[s1 * 2], q1 = gv[s1 * 2 + 1];
      lo.x += p0.x + p1.x; lo.y += p0.y + p1.y;
      lo.z += p0.z + p1.z; lo.w += p0.w + p1.w;
      hi.x += q0.x + q1.x; hi.y += q0.y + q1.y;
      hi.z += q0.z + q1.z; hi.w += q0.w + q1.w;
    }
    for (; k < end; k++) {
      int s = csr[k];
      float4 p = gv[s * 2], q = gv[s * 2 + 1];
      lo.x += p.x; lo.y += p.y; lo.z += p.z; lo.w += p.w;
      hi.x += q.x; hi.y += q.y; hi.z += q.z; hi.w += q.w;
    }
    float di = dinv[n];
    float4 sl = gv[n * 2], sh = gv[n * 2 + 1];   // self-loop
    float val[8] = {di * (lo.x + sl.x) + bb2[0], di * (lo.y + sl.y) + bb2[1],
                    di * (lo.z + sl.z) + bb2[2], di * (lo.w + sl.w) + bb2[3],
                    di * (hi.x + sh.x) + bb2[4], di * (hi.y + sh.y) + bb2[5],
                    di * (hi.z + sh.z) + bb2[6], di * (hi.w + sh.w) + bb2[7]};
    int gid = batch[n], goff = gid - batch0;
#pragma unroll
    for (int c = 0; c < 8; c++) {
      if (goff < 64) atomicAdd(&gpool[goff * 8 + c], val[c]);
      else           gAtomAdd(&gsum[gid * 8 + c], val[c]);
    }
  }
  __syncthreads();
  for (int i = tid; i < 64 * 8; i += 256) {
    int gid = batch0 + (i >> 3);
    float v = gpool[i];
    if (gid < N_GRAPHS && v != 0.f) gAtomAdd(&gsum[gid * 8 + (i & 7)], v);
  }
}

// ---------- mean divide (proven) ----------
__global__ void k_final(const float* __restrict__ gsum, const int* __restrict__ batch,
                        float* __restrict__ out) {
  int i = blockIdx.x * 256 + threadIdx.x;
  if (i >= N_GRAPHS * 8) return;
  int g = i >> 3;
  int lo = 0, hi = N_NODES;
  while (lo < hi) { int m = (lo + hi) >> 1; if (batch[m] < g) lo = m + 1; else hi = m; }
  int lo2 = lo, hi2 = N_NODES;
  while (lo2 < hi2) { int m = (lo2 + hi2) >> 1; if (batch[m] <= g) lo2 = m + 1; else hi2 = m; }
  float c = (float)(lo2 - lo);
  out[i] = gsum[i] / fmaxf(c, 1.f);
}

extern "C" void kernel_launch(void* const* d_in, const int* in_sizes, int n_in,
                              void* d_out, int out_size, void* d_ws, size_t ws_size,
                              hipStream_t stream) {
  const float* x    = (const float*)d_in[0];
  const int* ei     = (const int*)d_in[1];
  const int* batch  = (const int*)d_in[2];
  const float* W1   = (const float*)d_in[3];
  const float* b1   = (const float*)d_in[4];
  const float* W2   = (const float*)d_in[5];
  const float* b2   = (const float*)d_in[6];
  const int* srcp = ei;
  const int* dstp = ei + N_EDGES;
  float* out = (float*)d_out;

  // workspace carve (~41 MB)
  char* base = (char*)d_ws;
  size_t o = 0;
  auto carve = [&](size_t bytes) -> char* {
    char* p = base + o;
    o += (bytes + 255) & ~(size_t)255;
    return p;
  };
  int* bpad        = (int*)carve((size_t)NSB * 4);
  int* rcnt        = (int*)carve((size_t)NSB * 4);
  int* sboffs      = (int*)carve((size_t)(NSB + 1) * 4);
  unsigned* stage  = (unsigned*)carve((size_t)NSB * CAP * 4);   // 20 MB, 16-aligned regions
  int* csr         = (int*)carve((size_t)N_EDGES * 4);
  int* noffs       = (int*)carve((size_t)(N_NODES + 2) * 4);
  float* dinv      = (float*)carve((size_t)N_NODES * 4);
  float* xd8       = (float*)carve((size_t)N_NODES * 8 * 4);
  float* g2        = (float*)carve((size_t)N_NODES * 8 * 4);
  float* gsum      = (float*)carve((size_t)N_GRAPHS * 8 * 4);

  (void)hipFuncSetAttribute(reinterpret_cast<const void*>(&kAB_wc),
                            hipFuncAttributeMaxDynamicSharedMemorySize,
                            NSB * CAPB * 4);

  hipMemsetAsync(bpad, 0, (size_t)NSB * 4, stream);
  hipMemsetAsync(rcnt, 0, (size_t)NSB * 4, stream);
  hipMemsetAsync(gsum, 0, (size_t)N_GRAPHS * 8 * 4, stream);

  kAB_wc<<<WC_BLOCKS, WC_THREADS, NSB * CAPB * 4, stream>>>(srcp, dstp, bpad, rcnt, stage);
  k_bscan<<<1, 512, 0, stream>>>(rcnt, sboffs);
  kC_csr<<<NSB, 256, 0, stream>>>(stage, bpad, sboffs, x, noffs, dinv, xd8, csr);
  k_agg1<<<(N_NODES + 255) / 256, 256, 0, stream>>>(csr, noffs, xd8, dinv, W1, b1, W2, g2);
  k_agg2<<<(N_NODES + 255) / 256, 256, 0, stream>>>(csr, noffs, g2, dinv, b2, batch, gsum);
  k_final<<<64, 256, 0, stream>>>(gsum, batch, out);
}